// Round 13
// baseline (3925.138 us; speedup 1.0000x reference)
//
#include <hip/hip_runtime.h>
#include <math.h>

// NMSLoss3: sequential greedy-NMS pull/push loss.
// B=2, N=2048 proposals, G=64 gt boxes. Output: 2 floats [push/B, pull/B].
//
// R13: BRANCHLESS kill scan via Duff's-device switch entry.
// R12 post-mortem (3083us, VGPR=152, WRITE_SIZE~0): no scratch spill ever
// existed (no stores). Compiler rematerializes box loads from LDS inside
// each word's `if (aw_R)` block; the per-word branch serializes ds_read
// latency (~110cy x ~20 live words = the whole step time). Fix:
//  - straight-line word bodies (no aw!=0 guard, no K guard on mask update):
//    dead words self-neutralize (K = aw & ballot = 0); 32 ds_read_b128 +
//    IoU chains issue back-to-back and pipeline (LDS ~12cy/instr
//    throughput under ~52cy/word VALU).
//  - switch(p>>6) with fallthrough skips the all-dead front prefix
//    (sorted order => positions < p are dead): one uniform jump.
//  - NO pre-clear of selected bit: iou(i,i)~1 > THR, scan kills i
//    naturally; killed-1 corrects the count; E excludes i via gi==g.
//  - E-block (sg load + gtiou gather + logf) stays guarded: rare.
//  - next_p = branchless SALU min-chain over post-kill masks; prefetch of
//    boxes_s[next_p]/sgg_s[next_p] issued before tail bookkeeping.
// Carried: score-sorted bitonic preamble (measured bit-exact R4/R10/R12),
// ballot bookkeeping, rec boxes on lane g via __shfl, IEEE-div IoU with
// reference operand order ((area_a+area_b)-inter)+1e-12.

#define NMS_THR 0.5f
#define EPS_F 1e-6f
#define NPAD 2048
#define NWORDS 32
#define INF_POS 0x7fffffff

__device__ __forceinline__ unsigned long long init_mask(int r, int N) {
    long base = (long)r * 64;
    if (base + 64 <= N) return ~0ULL;
    if (base >= N) return 0ULL;
    return (~0ULL) >> (64 - (int)(N - base));
}

__global__ __launch_bounds__(64, 1) void nms_loss_kernel(
    const int* __restrict__ gt_inds,      // [B, N]
    const float* __restrict__ gt_bboxes,  // [B, G, 4]
    const float* __restrict__ proposals,  // [B, N, 5]
    float* __restrict__ out,              // [2]
    int N, int G, float inv_B)
{
    const int b    = blockIdx.x;
    const int lane = threadIdx.x;   // 0..63

    __shared__ unsigned long long skey[NPAD];   // 16KB; becomes sgg_s after sort
    __shared__ float4 boxes_s[NPAD];            // 32KB (sorted boxes)
    __shared__ float  gtiou[64 * 64];           // 16KB
    float2* sgg_s = reinterpret_cast<float2*>(skey);   // (score, gi bits), sorted

    const int*   gi_b   = gt_inds   + (size_t)b * N;
    const float* prop_b = proposals + (size_t)b * N * 5;
    const float* gtb    = gt_bboxes + (size_t)b * G * 4;

    // ---- build sort keys: ascending sort of ~(score_bits<<32 | ~j)
    //      => descending score, tie -> smaller original j first ----
    for (int j = lane; j < NPAD; j += 64) {
        unsigned long long key;
        if (j < N) {
            float s = prop_b[(size_t)j * 5 + 4];   // scores in (0,1] => bits order-isomorphic
            key = ~(((unsigned long long)__float_as_uint(s) << 32)
                    | (unsigned long long)(0xffffffffu - (unsigned)j));
        } else {
            key = ~0ULL;                            // pads sort to the end
        }
        skey[j] = key;
    }
    __syncthreads();

    // ---- bitonic sort (ascending), single wave, 2048 elements ----
    for (int k = 2; k <= NPAD; k <<= 1) {
        for (int jj = k >> 1; jj > 0; jj >>= 1) {
            for (int t = lane; t < NPAD; t += 64) {
                int l = t ^ jj;
                if (l > t) {
                    unsigned long long a = skey[t], c = skey[l];
                    bool up = ((t & k) == 0);
                    if ((a > c) == up) { skey[t] = c; skey[l] = a; }
                }
            }
            __syncthreads();
        }
    }

    // ---- stage sorted original indices, then overwrite skey with sgg ----
    // low 32 bits of key == original index j (since ~(0xffffffff-j) == j)
    unsigned idxs[NWORDS];
    #pragma unroll
    for (int w = 0; w < NWORDS; ++w) idxs[w] = (unsigned)skey[w * 64 + lane];
    __syncthreads();   // all key reads done before sgg_s overwrites skey

    #pragma unroll
    for (int w = 0; w < NWORDS; ++w) {
        int sp = w * 64 + lane;
        if (sp < N) {
            unsigned idx = idxs[w];
            const float* pr = prop_b + (size_t)idx * 5;
            boxes_s[sp] = make_float4(pr[0], pr[1], pr[2], pr[3]);
            sgg_s[sp]   = make_float2(pr[4], __int_as_float(gi_b[idx]));
        } else {
            boxes_s[sp] = make_float4(0.f, 0.f, 0.f, 0.f);
            sgg_s[sp]   = make_float2(1.0f, __int_as_float(0));
        }
    }

    // ---- gt iou table: gtiou[row*64+col], denom (area_row+area_col)-inter ----
    float4 gb = make_float4(0.f, 0.f, 0.f, 0.f);
    if (lane < G) {
        gb.x = gtb[lane * 4 + 0];
        gb.y = gtb[lane * 4 + 1];
        gb.z = gtb[lane * 4 + 2];
        gb.w = gtb[lane * 4 + 3];
    }
    float area_l = (gb.z - gb.x) * (gb.w - gb.y);
    for (int c = 0; c < G; ++c) {
        float cx1 = __shfl(gb.x, c), cy1 = __shfl(gb.y, c);
        float cx2 = __shfl(gb.z, c), cy2 = __shfl(gb.w, c);
        float area_c = (cx2 - cx1) * (cy2 - cy1);
        float ltx = fmaxf(gb.x, cx1), lty = fmaxf(gb.y, cy1);
        float rbx = fminf(gb.z, cx2), rby = fminf(gb.w, cy2);
        float w = fmaxf(rbx - ltx, 0.0f), h = fmaxf(rby - lty, 0.0f);
        float inter = w * h;
        if (lane < G)
            gtiou[lane * 64 + c] = inter / (area_l + area_c - inter + 1e-12f);
    }
    __syncthreads();

    // ---- alive masks (wave-uniform u64 per word) ----
#define DECL_AW(R) unsigned long long aw_##R = init_mask(R, N);
    DECL_AW(0)  DECL_AW(1)  DECL_AW(2)  DECL_AW(3)
    DECL_AW(4)  DECL_AW(5)  DECL_AW(6)  DECL_AW(7)
    DECL_AW(8)  DECL_AW(9)  DECL_AW(10) DECL_AW(11)
    DECL_AW(12) DECL_AW(13) DECL_AW(14) DECL_AW(15)
    DECL_AW(16) DECL_AW(17) DECL_AW(18) DECL_AW(19)
    DECL_AW(20) DECL_AW(21) DECL_AW(22) DECL_AW(23)
    DECL_AW(24) DECL_AW(25) DECL_AW(26) DECL_AW(27)
    DECL_AW(28) DECL_AW(29) DECL_AW(30) DECL_AW(31)
#undef DECL_AW

    int   alive_count = N;
    int   rec_reg = -1;          // lane g holds sorted position of rec[g] ...
    float rec_x = 0.f, rec_y = 0.f, rec_z = 0.f, rec_w = 0.f, rec_a = 0.f;
    float pull_s = 0.0f, push_s = 0.0f, pull_c = 0.0f, push_c = 0.0f;

    // first selection = sorted position 0 (bit NOT pre-cleared: the scan
    // kills the selected box naturally since iou(i,i) ~ 1 > THR).
    int p = (N > 0) ? 0 : -1;
    float4 nbi = make_float4(0.f, 0.f, 0.f, 0.f);
    float2 nsm = make_float2(1.0f, __int_as_float(0));
    if (p == 0) {
        nbi = boxes_s[0];
        nsm = sgg_s[0];
    }

    for (int step = 0; step < N && p >= 0; ++step) {
        const float4 bi = nbi;                   // prefetched broadcast data
        const float2 sm = nsm;
        const float  si = sm.x;
        const int    g  = __float_as_int(sm.y);
        const float  area_i = (bi.z - bi.x) * (bi.w - bi.y);

        const int  rec_g   = __shfl(rec_reg, g);
        const bool has_rec = rec_g >= 0;

        alive_count -= 1;                        // i removed
        const bool remaining = alive_count > 0;  // reference: any(alive2)

        if (has_rec) {
            pull_c += 1.0f;
            if (remaining) {
                float brx = __shfl(rec_x, g), bry = __shfl(rec_y, g);
                float brz = __shfl(rec_z, g), brw = __shfl(rec_w, g);
                float area_r = __shfl(rec_a, g);
                float ltx = fmaxf(brx, bi.x), lty = fmaxf(bry, bi.y);
                float rbx = fminf(brz, bi.z), rby = fminf(brw, bi.w);
                float w = fmaxf(rbx - ltx, 0.0f), h = fmaxf(rby - lty, 0.0f);
                float inter = w * h;
                float iou = inter / (area_r + area_i - inter + 1e-12f);
                float msi = fmaxf(iou, EPS_F);
                pull_s += -logf(1.0f - NMS_THR + msi) * si;
            }
        } else {
            if (lane == g) {
                rec_reg = p;
                rec_x = bi.x; rec_y = bi.y; rec_z = bi.z; rec_w = bi.w;
                rec_a = area_i;
            }
        }

        // -- branchless kill scan; switch entry skips the dead front prefix --
        float psum = 0.0f;
        int   pcnt = 0;
        int   killed_total = 0;   // includes i itself; corrected below
        int   cand = INF_POS;
        const float* __restrict__ gtrow = &gtiou[g * 64];

#define SCAN_WORD(R) \
        { \
            float4 bx = boxes_s[R * 64 + lane]; \
            float ar = (bx.z - bx.x) * (bx.w - bx.y); \
            float ltx = fmaxf(bi.x, bx.x), lty = fmaxf(bi.y, bx.y); \
            float rbx = fminf(bi.z, bx.z), rby = fminf(bi.w, bx.w); \
            float w = fmaxf(rbx - ltx, 0.0f), h = fmaxf(rby - lty, 0.0f); \
            float inter = w * h; \
            float iou = inter / (area_i + ar - inter + 1e-12f); \
            unsigned long long K = aw_##R & __ballot(iou > NMS_THR); \
            aw_##R &= ~K; \
            killed_total += __popcll(K); \
            if (K) { \
                float2 sgj = sgg_s[R * 64 + lane]; \
                int gj = __float_as_int(sgj.y); \
                unsigned long long E = \
                    K & __ballot((gj != g) && (iou > gtrow[gj])); \
                if (E) { \
                    pcnt += __popcll(E); \
                    bool elig = (E >> lane) & 1ULL; \
                    float pv = (-logf(1.0f + NMS_THR - iou) - logf(sgj.x)) \
                               * sgj.x; \
                    psum += elig ? pv : 0.0f; \
                } \
            } \
            int c_ = aw_##R ? (R * 64 + (int)__builtin_ctzll(aw_##R)) \
                            : INF_POS; \
            cand = (c_ < cand) ? c_ : cand; \
        }

        switch (p >> 6) {
        case 0:  SCAN_WORD(0)
        case 1:  SCAN_WORD(1)
        case 2:  SCAN_WORD(2)
        case 3:  SCAN_WORD(3)
        case 4:  SCAN_WORD(4)
        case 5:  SCAN_WORD(5)
        case 6:  SCAN_WORD(6)
        case 7:  SCAN_WORD(7)
        case 8:  SCAN_WORD(8)
        case 9:  SCAN_WORD(9)
        case 10: SCAN_WORD(10)
        case 11: SCAN_WORD(11)
        case 12: SCAN_WORD(12)
        case 13: SCAN_WORD(13)
        case 14: SCAN_WORD(14)
        case 15: SCAN_WORD(15)
        case 16: SCAN_WORD(16)
        case 17: SCAN_WORD(17)
        case 18: SCAN_WORD(18)
        case 19: SCAN_WORD(19)
        case 20: SCAN_WORD(20)
        case 21: SCAN_WORD(21)
        case 22: SCAN_WORD(22)
        case 23: SCAN_WORD(23)
        case 24: SCAN_WORD(24)
        case 25: SCAN_WORD(25)
        case 26: SCAN_WORD(26)
        case 27: SCAN_WORD(27)
        case 28: SCAN_WORD(28)
        case 29: SCAN_WORD(29)
        case 30: SCAN_WORD(30)
        case 31: SCAN_WORD(31)
        }
#undef SCAN_WORD

        // issue next-selection prefetch BEFORE tail bookkeeping (overlap)
        const int next_p = (cand == INF_POS) ? -1 : cand;
        if (next_p >= 0) {
            nbi = boxes_s[next_p];
            nsm = sgg_s[next_p];
        }

        killed_total -= 1;                 // i's own kill (always in K)
        alive_count  -= killed_total;
        if (pcnt > 0) {
            float ps = psum;
            for (int off = 32; off; off >>= 1) ps += __shfl_xor(ps, off);
            push_s += ps / (float)pcnt;
            push_c += (float)pcnt;
        }
        p = next_p;
    }

    // finalize: batch loss, averaged over B (PUSH_W = PULL_W = 1)
    float push_norm = push_s / (push_c + EPS_F);
    float pull_norm = pull_s / (pull_c + EPS_F);
    if (lane == 0) {
        atomicAdd(&out[0], push_norm * inv_B);
        atomicAdd(&out[1], pull_norm * inv_B);
    }
}

extern "C" void kernel_launch(void* const* d_in, const int* in_sizes, int n_in,
                              void* d_out, int out_size, void* d_ws, size_t ws_size,
                              hipStream_t stream) {
    // inputs (setup_inputs order): gt_inds[B,N] i32, anchor_gt_inds[B,N] i32,
    // gt_bboxes[B,G,4] f32, proposal_list[B,N,5] f32
    const int B = 2;
    const int N = in_sizes[1] / B;          // 2048
    const int G = in_sizes[2] / (B * 4);    // 64

    const int*   anchor_gt = (const int*)d_in[1];
    const float* gt_bboxes = (const float*)d_in[2];
    const float* proposals = (const float*)d_in[3];
    float* out = (float*)d_out;

    hipMemsetAsync(out, 0, 2 * sizeof(float), stream);
    nms_loss_kernel<<<B, 64, 0, stream>>>(anchor_gt, gt_bboxes, proposals,
                                          out, N, G, 1.0f / (float)B);
}